// Round 8
// baseline (2304.279 us; speedup 1.0000x reference)
//
#include <hip/hip_runtime.h>
#include <hip/hip_bf16.h>

typedef __bf16 bfx8 __attribute__((ext_vector_type(8)));
typedef __bf16 bfx4 __attribute__((ext_vector_type(4)));
typedef float f32x4 __attribute__((ext_vector_type(4)));

#define MFMA __builtin_amdgcn_mfma_f32_16x16x32_bf16

// Dims: S=32 T=32 B=512 H=1024 E=256 A=1024 VS=64 VT=70 START=1
// Separate launches (coop grid.sync measured ~35us/sync -- never again).
// Weights pre-swizzled fragment-major. gi emb-side hoisted into vocab
// tables g_tblS/g_tblT (R7: -200us). k_encpart frozen (R6).
// NEW (R8): h state (g_hb) stored FRAGMENT-MAJOR -- the only consumers
// (gru gh-GEMMs, k_hl) read it as an MFMA A-operand, so staging it
// through LDS every dispatch (16 ld+ds_write rounds + barrier + swizzled
// re-reads x96 dispatches) was pure layout conversion. Now gh/hl A-reads
// are 1KB coalesced wave streams identical to the weight path (R5's
// de-stage failed because its reads were 16B-scattered; this is the
// coalesced fix). gru LDS 76KB -> 12KB (handoff only), k_hl LDS -> 0.
// Layout: elem(b,j) at [((b>>4)*32 + (j>>5))*512 + ((b&15)+16*((j&31)>>3))*8
// + (j&7)] -- swz_rm's formula. k_init zeros are layout-invariant.

__device__ __attribute__((aligned(256))) float  g_h[512 * 1024];
__device__ __attribute__((aligned(256))) float  g_hpart[512 * 1024];
__device__ __attribute__((aligned(256))) __bf16 g_hb[2][512 * 1024];
__device__ __attribute__((aligned(256))) __bf16 g_Adec[512 * 1024];
__device__ __attribute__((aligned(256))) __bf16 g_enc_ops[(size_t)32 * 512 * 1024];
__device__ __attribute__((aligned(256))) __bf16 g_enc_part[(size_t)32 * 512 * 1024];
__device__ __attribute__((aligned(256))) __bf16 g_sWhhe[(size_t)3072 * 1024];   // fragment-major
__device__ __attribute__((aligned(256))) __bf16 g_sWihe[(size_t)3072 * 256];
__device__ __attribute__((aligned(256))) __bf16 g_sWhhd[(size_t)3072 * 1024];
__device__ __attribute__((aligned(256))) __bf16 g_sWihd[(size_t)3072 * 1280];
__device__ __attribute__((aligned(256))) __bf16 g_sWattnA[(size_t)1024 * 1024];
__device__ __attribute__((aligned(256))) __bf16 g_sWattnB[(size_t)1024 * 1024]; // W_attn[H:2H] frag-major
__device__ __attribute__((aligned(256))) __bf16 g_sWout[(size_t)128 * 1024];
__device__ __attribute__((aligned(256))) __bf16 g_embs[64 * 256];
__device__ __attribute__((aligned(256))) __bf16 g_embt[96 * 256];   // 70 used; pad for staging
__device__ __attribute__((aligned(256))) float  g_tblS[64 * 3072];
__device__ __attribute__((aligned(256))) float  g_tblT[70 * 3072];
__device__ __attribute__((aligned(256))) int    g_xsel[512];

__device__ __forceinline__ float fast_tanh(float x) {
    float cx = fminf(fmaxf(x, -15.f), 15.f);
    float e = __expf(-2.f * cx);
    return (1.f - e) / (1.f + e);
}

// ---------------------------------------------------------------------------
__global__ void k_cvt(const float* __restrict__ src, __bf16* __restrict__ dst,
                      int n4)
{
    int i = blockIdx.x * 256 + threadIdx.x;
    if (i >= n4) return;
    float4 v = ((const float4*)src)[i];
    __bf16 o[4] = {(__bf16)v.x, (__bf16)v.y, (__bf16)v.z, (__bf16)v.w};
    *(ushort2*)(dst + 4 * i) = *(ushort2*)o;
    *(ushort2*)(dst + 4 * i + 2) = *(ushort2*)(o + 2);
}

// Row-major f32 W[R][K] -> fragment-major bf16.
__global__ void swz_rm(const float* __restrict__ W, __bf16* __restrict__ out,
                       int nK, int total)
{
    int gid = blockIdx.x * 256 + threadIdx.x;
    if (gid >= total) return;
    int F = gid >> 6, L = gid & 63;
    int t = F / nK, c = F - t * nK;
    int K = nK * 32;
    const float* s = W + (size_t)(t * 16 + (L & 15)) * K + c * 32 + (L >> 4) * 8;
    __bf16 o[8];
#pragma unroll
    for (int u = 0; u < 8; u++) o[u] = (__bf16)s[u];
    *(uint4*)(out + (size_t)gid * 8) = *(uint4*)o;
}

// Column-gather: logical W'[n][k] = W[k*ldsrc + n]; n>=nguard -> 0.
__global__ void swz_cm(const float* __restrict__ W, __bf16* __restrict__ out,
                       int nK, int ldsrc, int nguard, int total)
{
    int gid = blockIdx.x * 256 + threadIdx.x;
    if (gid >= total) return;
    int F = gid >> 6, L = gid & 63;
    int t = F / nK, c = F - t * nK;
    int n = t * 16 + (L & 15);
    int k = c * 32 + (L >> 4) * 8;
    __bf16 o[8];
#pragma unroll
    for (int u = 0; u < 8; u++)
        o[u] = (n < nguard) ? (__bf16)W[(size_t)(k + u) * ldsrc + n] : (__bf16)0.f;
    *(uint4*)(out + (size_t)gid * 8) = *(uint4*)o;
}

__global__ void k_init(float* __restrict__ out)
{
    int idx = blockIdx.x * 256 + threadIdx.x;
    if (idx < 512 * 1024) { g_h[idx] = 0.f; g_hb[0][idx] = (__bf16)0.f; }
    if (idx < 512 * 70) out[idx] = (idx % 70 == 1) ? 1.f : 0.f;
}

// ---------------------------------------------------------------------------
// k_tbl: tbl[v][n] = emb[v][:] . W[n][cOff*32 : cOff*32+256]  (K=256, 8 frags)
// ---------------------------------------------------------------------------
__global__ __launch_bounds__(256) void k_tbl(
    const __bf16* __restrict__ emb, const __bf16* __restrict__ sW,
    int nKtot, int cOff, int vguard, float* __restrict__ tbl)
{
    __shared__ __bf16 sA[32 * 256];
    const int tid = threadIdx.x;
    const int w = tid >> 6, lane = tid & 63;
    const int r15 = lane & 15, q = lane >> 4;
    const int bx = blockIdx.x, m0 = blockIdx.y * 32;

#pragma unroll
    for (int i = 0; i < 4; i++) {
        int lin = tid + i * 256;
        int r = lin >> 5, U = lin & 31;
        uint4 v = *(const uint4*)(emb + (size_t)(m0 + r) * 256 + U * 8);
        *(uint4*)(sA + (r * 32 + (U ^ (r & 7))) * 8) = v;
    }
    __syncthreads();

    const size_t tb = (size_t)(bx * 4 + w);
    const __bf16* wp = sW + (tb * nKtot + cOff) * 512 + lane * 8;
    const int xk = r15 & 7;
    const int ar0 = r15 * 256, ar1 = (16 + r15) * 256;

    f32x4 acc[2];
    acc[0] = (f32x4){0.f, 0.f, 0.f, 0.f};
    acc[1] = (f32x4){0.f, 0.f, 0.f, 0.f};
#pragma unroll
    for (int c = 0; c < 8; c++) {
        int us = ((c * 4 + q) ^ xk) * 8;
        bfx8 a0 = *(const bfx8*)(sA + ar0 + us);
        bfx8 a1 = *(const bfx8*)(sA + ar1 + us);
        bfx8 wv = *(const bfx8*)(wp + c * 512);
        acc[0] = MFMA(a0, wv, acc[0], 0, 0, 0);
        acc[1] = MFMA(a1, wv, acc[1], 0, 0, 0);
    }
    const int n = bx * 64 + w * 16 + r15;
#pragma unroll
    for (int ms = 0; ms < 2; ms++)
#pragma unroll
        for (int reg = 0; reg < 4; reg++) {
            int row = m0 + ms * 16 + q * 4 + reg;
            if (row < vguard)
                tbl[(size_t)row * 3072 + n] = acc[ms][reg];
        }
}

// ---------------------------------------------------------------------------
// k_encpart (frozen R6): XCD-swizzled, A dbuf 32KB K-chunks, LDS C-stage.
// ---------------------------------------------------------------------------
__global__ __launch_bounds__(512, 4) void k_encpart(
    const __bf16* __restrict__ Amat, const __bf16* __restrict__ sW,
    __bf16* __restrict__ Cout)
{
    __shared__ __bf16 sA[2][64 * 256];   // 2 x 32 KB
    const int tid = threadIdx.x;
    const int w = tid >> 6, lane = tid & 63;
    const int r15 = lane & 15, q = lane >> 4;
    const int sw = (blockIdx.x & 7) * 128 + (blockIdx.x >> 3);
    const int nx = sw & 3;
    const int n0 = nx * 256, m0 = (sw >> 2) * 64;

    int sr[4], sv[4], so[4];
#pragma unroll
    for (int i = 0; i < 4; i++) {
        int lin = tid + i * 512;
        sr[i] = lin >> 5;
        sv[i] = lin & 31;
        so[i] = (sr[i] * 32 + (sv[i] ^ (sr[i] & 7))) * 8;
    }

    uint4 regs[4];
#pragma unroll
    for (int i = 0; i < 4; i++)
        regs[i] = *(const uint4*)(Amat + (size_t)(m0 + sr[i]) * 1024 + sv[i] * 8);
#pragma unroll
    for (int i = 0; i < 4; i++)
        *(uint4*)(&sA[0][so[i]]) = regs[i];
    __syncthreads();

    const int xk = r15 & 7;
    f32x4 acc[2][4];
#pragma unroll
    for (int nn = 0; nn < 2; nn++)
#pragma unroll
        for (int mf = 0; mf < 4; mf++) acc[nn][mf] = (f32x4){0.f, 0.f, 0.f, 0.f};

    const __bf16* wp0 = sW + ((size_t)(nx * 16 + w * 2) * 32) * 512 + lane * 8;
    const __bf16* wp1 = wp0 + 32 * 512;
    const int ar0 = r15 * 256;
    const int ar1 = (16 + r15) * 256;
    const int ar2 = (32 + r15) * 256;
    const int ar3 = (48 + r15) * 256;

    for (int kc = 0; kc < 4; kc++) {
        if (kc < 3) {
#pragma unroll
            for (int i = 0; i < 4; i++)
                regs[i] = *(const uint4*)(Amat + (size_t)(m0 + sr[i]) * 1024 +
                                          (kc + 1) * 256 + sv[i] * 8);
        }
        const __bf16* sAb = sA[kc & 1];
        const __bf16* wq0 = wp0 + kc * 8 * 512;
        const __bf16* wq1 = wp1 + kc * 8 * 512;
#pragma unroll
        for (int c = 0; c < 8; c++) {
            int us = ((c * 4 + q) ^ xk) * 8;
            bfx8 a0 = *(const bfx8*)(sAb + ar0 + us);
            bfx8 a1 = *(const bfx8*)(sAb + ar1 + us);
            bfx8 a2 = *(const bfx8*)(sAb + ar2 + us);
            bfx8 a3 = *(const bfx8*)(sAb + ar3 + us);
            bfx8 w0 = *(const bfx8*)(wq0 + c * 512);
            bfx8 w1 = *(const bfx8*)(wq1 + c * 512);
            acc[0][0] = MFMA(a0, w0, acc[0][0], 0, 0, 0);
            acc[0][1] = MFMA(a1, w0, acc[0][1], 0, 0, 0);
            acc[0][2] = MFMA(a2, w0, acc[0][2], 0, 0, 0);
            acc[0][3] = MFMA(a3, w0, acc[0][3], 0, 0, 0);
            acc[1][0] = MFMA(a0, w1, acc[1][0], 0, 0, 0);
            acc[1][1] = MFMA(a1, w1, acc[1][1], 0, 0, 0);
            acc[1][2] = MFMA(a2, w1, acc[1][2], 0, 0, 0);
            acc[1][3] = MFMA(a3, w1, acc[1][3], 0, 0, 0);
        }
        if (kc < 3) {
#pragma unroll
            for (int i = 0; i < 4; i++)
                *(uint4*)(&sA[(kc + 1) & 1][so[i]]) = regs[i];
            __syncthreads();
        }
    }

    __bf16* sC = sA[0];
#pragma unroll
    for (int nn = 0; nn < 2; nn++) {
        const int cl = (w * 2 + nn) * 16 + r15;
#pragma unroll
        for (int mf = 0; mf < 4; mf++) {
#pragma unroll
            for (int reg = 0; reg < 4; reg++) {
                int row = mf * 16 + q * 4 + reg;
                sC[row * 256 + cl] = (__bf16)acc[nn][mf][reg];
            }
        }
    }
    __syncthreads();
#pragma unroll
    for (int i = 0; i < 4; i++) {
        int lin = tid + i * 512;
        int row = lin >> 5, unit = lin & 31;
        *(uint4*)(Cout + (size_t)(m0 + row) * 1024 + n0 + unit * 8) =
            *(const uint4*)(sC + row * 256 + unit * 8);
    }
}

// ---------------------------------------------------------------------------
// GH_BODY_G: gh fragment from FRAG-MAJOR global h (coalesced 1KB streams,
// same shape as weight loads). GI_BODY: Adec direct (row-major, 64B segs).
// ---------------------------------------------------------------------------
#define GH_BODY_G(ACC)                                            \
    {                                                             \
        bfx8 a0 = *(const bfx8*)(H0 + c * 512);                   \
        bfx8 a1 = *(const bfx8*)(H1 + c * 512);                   \
        bfx8 w0 = *(const bfx8*)(xp0 + c * 512);                  \
        bfx8 w1 = *(const bfx8*)(xp1 + c * 512);                  \
        bfx8 w2 = *(const bfx8*)(xp2 + c * 512);                  \
        ACC[0][0] = MFMA(a0, w0, ACC[0][0], 0, 0, 0);             \
        ACC[0][1] = MFMA(a1, w0, ACC[0][1], 0, 0, 0);             \
        ACC[1][0] = MFMA(a0, w1, ACC[1][0], 0, 0, 0);             \
        ACC[1][1] = MFMA(a1, w1, ACC[1][1], 0, 0, 0);             \
        ACC[2][0] = MFMA(a0, w2, ACC[2][0], 0, 0, 0);             \
        ACC[2][1] = MFMA(a1, w2, ACC[2][1], 0, 0, 0);             \
    }

#define GI_BODY(ACC)                                              \
    {                                                             \
        bfx8 a0 = *(const bfx8*)(A0 + c * 32);                    \
        bfx8 a1 = *(const bfx8*)(A1 + c * 32);                    \
        bfx8 w0 = *(const bfx8*)(wp0 + c * 512);                  \
        bfx8 w1 = *(const bfx8*)(wp1 + c * 512);                  \
        bfx8 w2 = *(const bfx8*)(wp2 + c * 512);                  \
        ACC[0][0] = MFMA(a0, w0, ACC[0][0], 0, 0, 0);             \
        ACC[0][1] = MFMA(a1, w0, ACC[0][1], 0, 0, 0);             \
        ACC[1][0] = MFMA(a0, w1, ACC[1][0], 0, 0, 0);             \
        ACC[1][1] = MFMA(a1, w1, ACC[1][1], 0, 0, 0);             \
        ACC[2][0] = MFMA(a0, w2, ACC[2][0], 0, 0, 0);             \
        ACC[2][1] = MFMA(a1, w2, ACC[2][1], 0, 0, 0);             \
    }

// frag-major offset for h element (b, j); b16 = b>>4 tile, jj = j.
__device__ __forceinline__ size_t hfrag_off(int b, int jj) {
    return ((size_t)(b >> 4) * 32 + (jj >> 5)) * 512 +
           (size_t)(((b & 15) + 16 * ((jj & 31) >> 3)) * 8 + (jj & 7));
}

// ---------------------------------------------------------------------------
// gru_enc: grid (32 j, 16 m) x 256 thr, LDS 12KB. gi from g_tblS (epilogue
// gather). All 4 waves gh via frag-major global streams: w<2 c[0,16),
// w>=2 c[16,32) -> sGh handoff. No A staging, one barrier.
// ---------------------------------------------------------------------------
__global__ __launch_bounds__(256, 2) void gru_enc(
    const __bf16* __restrict__ hb_in, __bf16* __restrict__ hb_out,
    const float* __restrict__ b1, const float* __restrict__ b2,
    const int* __restrict__ src_t, int enc_t)
{
    __shared__ __align__(16) float sGh[3072];   // 12 KB
    const int tid = threadIdx.x;
    const int w = tid >> 6, lane = tid & 63;
    const int r15 = lane & 15, q = lane >> 4;
    const int j0 = blockIdx.x * 32, m0 = blockIdx.y * 32;
    const int jsub = w & 1;

    const size_t tb = (size_t)(blockIdx.x * 2 + jsub);
    f32x4 acc[3][2];
#pragma unroll
    for (int s = 0; s < 3; s++)
#pragma unroll
        for (int ms = 0; ms < 2; ms++) acc[s][ms] = (f32x4){0.f, 0.f, 0.f, 0.f};

    const __bf16* H0 = hb_in + (size_t)m0 * 1024 + lane * 8;   // (m0>>4)*32*512
    const __bf16* H1 = H0 + 16384;                             // next 16-b tile
    const __bf16* xp0 = g_sWhhe + (tb * 32) * 512 + lane * 8;
    const __bf16* xp1 = g_sWhhe + ((tb + 64) * 32) * 512 + lane * 8;
    const __bf16* xp2 = g_sWhhe + ((tb + 128) * 32) * 512 + lane * 8;
    const int cbeg = (w < 2) ? 0 : 16;
#pragma unroll 8
    for (int c = cbeg; c < cbeg + 16; c++) GH_BODY_G(acc)

    if (w >= 2) {
#pragma unroll
        for (int s = 0; s < 3; s++)
#pragma unroll
            for (int ms = 0; ms < 2; ms++)
#pragma unroll
                for (int reg = 0; reg < 4; reg++)
                    sGh[((s * 2 + jsub) * 32 + ms * 16 + q * 4 + reg) * 16 + r15] =
                        acc[s][ms][reg];
    }
    __syncthreads();
    if (w < 2) {
        const int jj = j0 + jsub * 16 + r15;
        const float bb1[3] = {b1[jj], b1[1024 + jj], b1[2048 + jj]};
        const float bb2[3] = {b2[jj], b2[1024 + jj], b2[2048 + jj]};
#pragma unroll
        for (int ms = 0; ms < 2; ms++) {
#pragma unroll
            for (int reg = 0; reg < 4; reg++) {
                int bl = ms * 16 + q * 4 + reg;
                int b_ = m0 + bl;
                int xv = src_t[b_];
                xv = (xv < 0) ? 0 : (xv > 63 ? 63 : xv);
                const float* tv = g_tblS + (size_t)xv * 3072 + jj;
                float gh0 = acc[0][ms][reg] + bb1[0] +
                            sGh[((0 * 2 + jsub) * 32 + bl) * 16 + r15];
                float gh1 = acc[1][ms][reg] + bb1[1] +
                            sGh[((1 * 2 + jsub) * 32 + bl) * 16 + r15];
                float gh2 = acc[2][ms][reg] + bb1[2] +
                            sGh[((2 * 2 + jsub) * 32 + bl) * 16 + r15];
                float gi0 = tv[0]    + bb2[0];
                float gi1 = tv[1024] + bb2[1];
                float gi2 = tv[2048] + bb2[2];
                float r = 1.f / (1.f + __expf(-(gi0 + gh0)));
                float z = 1.f / (1.f + __expf(-(gi1 + gh1)));
                float n = fast_tanh(gi2 + r * gh2);
                size_t off = (size_t)b_ * 1024 + jj;
                float hv = (1.f - z) * n + z * g_h[off];
                g_h[off] = hv;
                hb_out[hfrag_off(b_, jj)] = (__bf16)hv;
                g_enc_ops[(size_t)enc_t * 524288 + off] = (__bf16)hv;
            }
        }
    }
}

// ---------------------------------------------------------------------------
// gru_dec: waves 0-1 gh (32 frags, frag-major global h), waves 2-3 gi
// ctx-part (32 frags, Adec direct) -> sGi handoff. Emb gi from g_tblT.
// LDS 12KB, one barrier.
// ---------------------------------------------------------------------------
__global__ __launch_bounds__(256, 2) void gru_dec(
    const __bf16* __restrict__ hb_in, __bf16* __restrict__ hb_out,
    const float* __restrict__ b1, const float* __restrict__ b2)
{
    __shared__ __align__(16) float sGi[3072];   // 12 KB
    const int tid = threadIdx.x;
    const int w = tid >> 6, lane = tid & 63;
    const int r15 = lane & 15, q = lane >> 4;
    const int j0 = blockIdx.x * 32, m0 = blockIdx.y * 32;
    const int jsub = w & 1;

    const size_t tb = (size_t)(blockIdx.x * 2 + jsub);
    f32x4 acc[3][2];
#pragma unroll
    for (int s = 0; s < 3; s++)
#pragma unroll
        for (int ms = 0; ms < 2; ms++) acc[s][ms] = (f32x4){0.f, 0.f, 0.f, 0.f};

    if (w < 2) {
        const __bf16* H0 = hb_in + (size_t)m0 * 1024 + lane * 8;
        const __bf16* H1 = H0 + 16384;
        const __bf16* xp0 = g_sWhhd + (tb * 32) * 512 + lane * 8;
        const __bf16* xp1 = g_sWhhd + ((tb + 64) * 32) * 512 + lane * 8;
        const __bf16* xp2 = g_sWhhd + ((tb + 128) * 32) * 512 + lane * 8;
#pragma unroll 8
        for (int c = 0; c < 32; c++) GH_BODY_G(acc)
    } else {
        const __bf16* A0 = g_Adec + (size_t)(m0 + r15) * 1024 + q * 8;
        const __bf16* A1 = A0 + 16 * 1024;
        const __bf16* wp0 = g_sWihd + (tb * 40) * 512 + lane * 8;
        const __bf16* wp1 = g_sWihd + ((tb + 64) * 40) * 512 + lane * 8;
        const __bf16* wp2 = g_sWihd + ((tb + 128) * 40) * 512 + lane * 8;
#pragma unroll 8
        for (int c = 0; c < 32; c++) GI_BODY(acc)
#pragma unroll
        for (int s = 0; s < 3; s++)
#pragma unroll
            for (int ms = 0; ms < 2; ms++)
#pragma unroll
                for (int reg = 0; reg < 4; reg++)
                    sGi[((s * 2 + jsub) * 32 + ms * 16 + q * 4 + reg) * 16 + r15] =
                        acc[s][ms][reg];
    }
    __syncthreads();
    if (w < 2) {
        const int jj = j0 + jsub * 16 + r15;
        const float bb1[3] = {b1[jj], b1[1024 + jj], b1[2048 + jj]};
        const float bb2[3] = {b2[jj], b2[1024 + jj], b2[2048 + jj]};
#pragma unroll
        for (int ms = 0; ms < 2; ms++) {
#pragma unroll
            for (int reg = 0; reg < 4; reg++) {
                int bl = ms * 16 + q * 4 + reg;
                int b_ = m0 + bl;
                const float* tv = g_tblT + (size_t)g_xsel[b_] * 3072 + jj;
                float gh0 = acc[0][ms][reg] + bb1[0];
                float gh1 = acc[1][ms][reg] + bb1[1];
                float gh2 = acc[2][ms][reg] + bb1[2];
                float gi0 = sGi[((0 * 2 + jsub) * 32 + bl) * 16 + r15] +
                            tv[0]    + bb2[0];
                float gi1 = sGi[((1 * 2 + jsub) * 32 + bl) * 16 + r15] +
                            tv[1024] + bb2[1];
                float gi2 = sGi[((2 * 2 + jsub) * 32 + bl) * 16 + r15] +
                            tv[2048] + bb2[2];
                float r = 1.f / (1.f + __expf(-(gi0 + gh0)));
                float z = 1.f / (1.f + __expf(-(gi1 + gh1)));
                float n = fast_tanh(gi2 + r * gh2);
                size_t off = (size_t)b_ * 1024 + jj;
                float hv = (1.f - z) * n + z * g_h[off];
                g_h[off] = hv;
                hb_out[hfrag_off(b_, jj)] = (__bf16)hv;
            }
        }
    }
}

// ---------------------------------------------------------------------------
// k_hl: [hpart | logits] from frag-major h. 0 LDS, 0 barriers -- pure
// stream: 2 A-loads + 1 W-load + 2 MFMA per K-frag. grid (18, 16).
// ---------------------------------------------------------------------------
__global__ __launch_bounds__(256) void k_hl(
    const __bf16* __restrict__ src, const float* __restrict__ battn,
    const float* __restrict__ bout, int lrow, float* __restrict__ outp)
{
    const int tid = threadIdx.x;
    const int w = tid >> 6, lane = tid & 63;
    const int r15 = lane & 15, q = lane >> 4;
    const int bx = blockIdx.x, m0 = blockIdx.y * 32;

    const __bf16* sW;
    int n;
    if (bx < 16) {
        sW = g_sWattnA;
        n = bx * 64 + w * 16 + r15;
    } else {
        if (lrow < 0) return;
        sW = g_sWout;
        n = (bx - 16) * 64 + w * 16 + r15;
    }
    const size_t tb = (size_t)((bx < 16 ? bx : bx - 16) * 4 + w);
    const __bf16* wp = sW + (tb * 32) * 512 + lane * 8;
    const __bf16* H0 = src + (size_t)m0 * 1024 + lane * 8;
    const __bf16* H1 = H0 + 16384;

    f32x4 acc[2];
    acc[0] = (f32x4){0.f, 0.f, 0.f, 0.f};
    acc[1] = (f32x4){0.f, 0.f, 0.f, 0.f};
#pragma unroll 8
    for (int c = 0; c < 32; c++) {
        bfx8 a0 = *(const bfx8*)(H0 + c * 512);
        bfx8 a1 = *(const bfx8*)(H1 + c * 512);
        bfx8 wv = *(const bfx8*)(wp + c * 512);
        acc[0] = MFMA(a0, wv, acc[0], 0, 0, 0);
        acc[1] = MFMA(a1, wv, acc[1], 0, 0, 0);
    }

    if (bx < 16) {
        float bv = battn[n];
#pragma unroll
        for (int ms = 0; ms < 2; ms++)
#pragma unroll
            for (int reg = 0; reg < 4; reg++)
                g_hpart[(size_t)(m0 + ms * 16 + q * 4 + reg) * 1024 + n] =
                    acc[ms][reg] + bv;
    } else if (n < 70) {
        float bv = bout[n];
#pragma unroll
        for (int ms = 0; ms < 2; ms++)
#pragma unroll
            for (int reg = 0; reg < 4; reg++)
                outp[(size_t)lrow * 35840 +
                     (size_t)(m0 + ms * 16 + q * 4 + reg) * 70 + n] =
                    acc[ms][reg] + bv;
    }
}

// ---------------------------------------------------------------------------
// Attention step: x-select (-> g_xsel) + scores + softmax + alpha out + ctx.
// One block per batch b.
// ---------------------------------------------------------------------------
__global__ __launch_bounds__(256) void k_attn(
    int j, const int* __restrict__ target, const int* __restrict__ tf,
    const float* __restrict__ v_attn, float* __restrict__ out)
{
    const int b = blockIdx.x, tid = threadIdx.x;
    const int lane = tid & 63, wave = tid >> 6;
    __shared__ float sc[32], sal[32];
    __shared__ int sx;
    if (wave == 0) {
        int xv;
        if (j == 0) xv = target[b];
        else if (*tf) xv = target[j * 512 + b];
        else {
            const float* row = out + (size_t)j * 35840 + b * 70;
            float bv = row[lane]; int bi = lane;
            if (lane < 6) {
                float v2 = row[lane + 64];
                if (v2 > bv) { bv = v2; bi = lane + 64; }
            }
#pragma unroll
            for (int off = 32; off; off >>= 1) {
                float ov = __shfl_down(bv, off);
                int   oi = __shfl_down(bi, off);
                if (ov > bv || (ov == bv && oi < bi)) { bv = ov; bi = oi; }
            }
            xv = bi;
        }
        if (lane == 0) sx = (xv < 0) ? 0 : (xv > 69 ? 69 : xv);
    }
    float hpv[16], vsv[16];
    {
        const float* hp = g_hpart + (size_t)b * 1024;
#pragma unroll
        for (int u = 0; u < 8; u++) {
            hpv[u]     = hp[lane * 8 + u];
            hpv[8 + u] = hp[512 + lane * 8 + u];
            vsv[u]     = v_attn[lane * 8 + u];
            vsv[8 + u] = v_attn[512 + lane * 8 + u];
        }
    }
    __syncthreads();
    if (tid == 0) g_xsel[b] = sx;
    for (int s = wave * 8; s < wave * 8 + 8; s++) {
        const __bf16* ep = g_enc_part + ((size_t)s * 512 + b) * 1024;
        bfx8 e0 = *(const bfx8*)(ep + lane * 8);
        bfx8 e1 = *(const bfx8*)(ep + 512 + lane * 8);
        float part = 0.f;
#pragma unroll
        for (int u = 0; u < 8; u++) {
            part += vsv[u]     * fast_tanh((float)e0[u] + hpv[u]);
            part += vsv[8 + u] * fast_tanh((float)e1[u] + hpv[8 + u]);
        }
#pragma unroll
        for (int off = 32; off; off >>= 1) part += __shfl_down(part, off);
        if (lane == 0) sc[s] = part;
    }
    __syncthreads();
    float mx = sc[0];
#pragma unroll
    for (int s = 1; s < 32; s++) mx = fmaxf(mx, sc[s]);
    float den = 0.f;
#pragma unroll
    for (int s = 0; s < 32; s++) den += __expf(sc[s] - mx);
    float rden = 1.f / den;
    if (tid < 32) {
        float al = __expf(sc[tid] - mx) * rden;
        sal[tid] = al;
        out[1146880 + (size_t)j * 16384 + b * 32 + tid] = al;
    }
    __syncthreads();
    float c0 = 0, c1 = 0, c2 = 0, c3 = 0;
    const __bf16* eo = g_enc_ops + (size_t)b * 1024 + tid * 4;
#pragma unroll 4
    for (int s = 0; s < 32; s++) {
        bfx4 e = *(const bfx4*)(eo + (size_t)s * 524288);
        float al = sal[s];
        c0 += al * (float)e[0]; c1 += al * (float)e[1];
        c2 += al * (float)e[2]; c3 += al * (float)e[3];
    }
    bfx4 o = {(__bf16)c0, (__bf16)c1, (__bf16)c2, (__bf16)c3};
    *(bfx4*)(&g_Adec[(size_t)b * 1024 + tid * 4]) = o;
}

// ---------------------------------------------------------------------------
extern "C" void kernel_launch(void* const* d_in, const int* in_sizes, int n_in,
                              void* d_out, int out_size, void* d_ws, size_t ws_size,
                              hipStream_t stream)
{
    const int*   source   = (const int*)d_in[0];
    const int*   target   = (const int*)d_in[1];
    const int*   tf       = (const int*)d_in[2];
    const float* emb_src  = (const float*)d_in[3];
    const float* W_ih_enc = (const float*)d_in[4];
    const float* W_hh_enc = (const float*)d_in[5];
    const float* b_ih_enc = (const float*)d_in[6];
    const float* b_hh_enc = (const float*)d_in[7];
    const float* emb_tgt  = (const float*)d_in[8];
    const float* W_attn   = (const float*)d_in[9];
    const float* b_attn   = (const float*)d_in[10];
    const float* v_attn   = (const float*)d_in[11];
    const float* W_ih_dec = (const float*)d_in[12];
    const float* W_hh_dec = (const float*)d_in[13];
    const float* b_ih_dec = (const float*)d_in[14];
    const float* b_hh_dec = (const float*)d_in[15];
    const float* W_out    = (const float*)d_in[16];
    const float* b_out    = (const float*)d_in[17];
    float* out = (float*)d_out;

    void *p_hb, *p_sWhhe, *p_sWihe, *p_sWhhd, *p_sWihd, *p_sWattnA, *p_sWattnB,
         *p_sWout, *p_embs, *p_embt, *p_enc_ops, *p_enc_part, *p_tblS, *p_tblT;
    hipGetSymbolAddress(&p_hb,       HIP_SYMBOL(g_hb));
    hipGetSymbolAddress(&p_sWhhe,    HIP_SYMBOL(g_sWhhe));
    hipGetSymbolAddress(&p_sWihe,    HIP_SYMBOL(g_sWihe));
    hipGetSymbolAddress(&p_sWhhd,    HIP_SYMBOL(g_sWhhd));
    hipGetSymbolAddress(&p_sWihd,    HIP_SYMBOL(g_sWihd));
    hipGetSymbolAddress(&p_sWattnA,  HIP_SYMBOL(g_sWattnA));
    hipGetSymbolAddress(&p_sWattnB,  HIP_SYMBOL(g_sWattnB));
    hipGetSymbolAddress(&p_sWout,    HIP_SYMBOL(g_sWout));
    hipGetSymbolAddress(&p_embs,     HIP_SYMBOL(g_embs));
    hipGetSymbolAddress(&p_embt,     HIP_SYMBOL(g_embt));
    hipGetSymbolAddress(&p_enc_ops,  HIP_SYMBOL(g_enc_ops));
    hipGetSymbolAddress(&p_enc_part, HIP_SYMBOL(g_enc_part));
    hipGetSymbolAddress(&p_tblS,     HIP_SYMBOL(g_tblS));
    hipGetSymbolAddress(&p_tblT,     HIP_SYMBOL(g_tblT));
    __bf16* hb0 = (__bf16*)p_hb;
    __bf16* hb1 = hb0 + 512 * 1024;

    // ---- one-time setup ----
    k_cvt<<<16, 256, 0, stream>>>(emb_src, (__bf16*)p_embs, 64 * 256 / 4);
    k_cvt<<<18, 256, 0, stream>>>(emb_tgt, (__bf16*)p_embt, 70 * 256 / 4);
    swz_rm<<<1536, 256, 0, stream>>>(W_hh_enc, (__bf16*)p_sWhhe, 32, 393216);
    swz_rm<<<384,  256, 0, stream>>>(W_ih_enc, (__bf16*)p_sWihe, 8,  98304);
    swz_rm<<<1536, 256, 0, stream>>>(W_hh_dec, (__bf16*)p_sWhhd, 32, 393216);
    swz_rm<<<1920, 256, 0, stream>>>(W_ih_dec, (__bf16*)p_sWihd, 40, 491520);
    swz_cm<<<512,  256, 0, stream>>>(W_attn, (__bf16*)p_sWattnA, 32, 1024, 1024, 131072);
    swz_cm<<<512,  256, 0, stream>>>(W_attn + (size_t)1024 * 1024,
                                     (__bf16*)p_sWattnB, 32, 1024, 1024, 131072);
    swz_cm<<<64,   256, 0, stream>>>(W_out,  (__bf16*)p_sWout,   32, 70,   70,   16384);
    // gi tables: tblS = emb_src @ W_ih_enc^T ; tblT = emb_tgt @ W_ih_dec[:,H:]^T
    k_tbl<<<dim3(48, 2), 256, 0, stream>>>(
        (__bf16*)p_embs, (__bf16*)p_sWihe, 8,  0,  64, (float*)p_tblS);
    k_tbl<<<dim3(48, 3), 256, 0, stream>>>(
        (__bf16*)p_embt, (__bf16*)p_sWihd, 40, 32, 70, (float*)p_tblT);
    k_init<<<2048, 256, 0, stream>>>(out);

    // -------- Encoder: 32 steps (hb frag-major; zeros layout-invariant) ----
    for (int t = 0; t < 32; t++) {
        __bf16* hin  = (t & 1) ? hb1 : hb0;
        __bf16* hout = (t & 1) ? hb0 : hb1;
        gru_enc<<<dim3(32, 16), 256, 0, stream>>>(
            hin, hout, b_hh_enc, b_ih_enc, source + t * 512, t);
    }
    // h_enc lands in hb0

    // enc_part = enc_ops @ W_attn[H:2H]^T  (frag-major weights, no bias)
    k_encpart<<<dim3(1024), 512, 0, stream>>>(
        (__bf16*)p_enc_ops, (__bf16*)p_sWattnB, (__bf16*)p_enc_part);

    // hpart for step 0
    k_hl<<<dim3(18, 16), 256, 0, stream>>>(hb0, b_attn, b_out, -1, out);

    // -------- Decoder: 31 steps --------
    for (int j = 0; j < 31; j++) {
        __bf16* hin  = (j & 1) ? hb1 : hb0;
        __bf16* hout = (j & 1) ? hb0 : hb1;
        k_attn<<<512, 256, 0, stream>>>(j, target, tf, v_attn, out);
        gru_dec<<<dim3(32, 16), 256, 0, stream>>>(hin, hout, b_hh_dec, b_ih_dec);
        k_hl<<<dim3(18, 16), 256, 0, stream>>>(hout, b_attn, b_out, j + 1, out);
    }
}

// Round 9
// 2061.274 us; speedup vs baseline: 1.1179x; 1.1179x over previous
//
#include <hip/hip_runtime.h>
#include <hip/hip_bf16.h>

typedef __bf16 bfx8 __attribute__((ext_vector_type(8)));
typedef __bf16 bfx4 __attribute__((ext_vector_type(4)));
typedef float f32x4 __attribute__((ext_vector_type(4)));

#define MFMA __builtin_amdgcn_mfma_f32_16x16x32_bf16

// Dims: S=32 T=32 B=512 H=1024 E=256 A=1024 VS=64 VT=70 START=1
// R7 structure (best measured: 2087us). Separate launches (coop grid.sync
// ~35us/sync). Weights fragment-major; gi emb-side hoisted into vocab
// tables g_tblS/g_tblT (R7: -200us). A-operands LDS-staged -- R5 (scattered
// direct reads, +577us) and R8 (frag-major h direct streams, +217us) both
// proved de-staging loses; the stage is load-bearing.
// NEW (R9): the stage itself now uses __builtin_amdgcn_global_load_lds
// (width 16) -- no VGPR round-trip, no per-round address VALU. LDS dest is
// linear (HW: wave-uniform base + lane*16); the XOR swizzle U^(r&7) is
// applied to the per-lane GLOBAL source instead (involution within 128B
// windows -> still fully coalesced; final LDS image byte-identical to R7,
// K-loop readers unchanged). Applied to gru_enc/gru_dec/k_hl (96 dispatches).

__device__ __attribute__((aligned(256))) float  g_h[512 * 1024];
__device__ __attribute__((aligned(256))) float  g_hpart[512 * 1024];
__device__ __attribute__((aligned(256))) __bf16 g_hb[2][512 * 1024];
__device__ __attribute__((aligned(256))) __bf16 g_Adec[512 * 1024];
__device__ __attribute__((aligned(256))) __bf16 g_enc_ops[(size_t)32 * 512 * 1024];
__device__ __attribute__((aligned(256))) __bf16 g_enc_part[(size_t)32 * 512 * 1024];
__device__ __attribute__((aligned(256))) __bf16 g_sWhhe[(size_t)3072 * 1024];   // fragment-major
__device__ __attribute__((aligned(256))) __bf16 g_sWihe[(size_t)3072 * 256];
__device__ __attribute__((aligned(256))) __bf16 g_sWhhd[(size_t)3072 * 1024];
__device__ __attribute__((aligned(256))) __bf16 g_sWihd[(size_t)3072 * 1280];
__device__ __attribute__((aligned(256))) __bf16 g_sWattnA[(size_t)1024 * 1024];
__device__ __attribute__((aligned(256))) __bf16 g_sWattnB[(size_t)1024 * 1024]; // W_attn[H:2H] frag-major
__device__ __attribute__((aligned(256))) __bf16 g_sWout[(size_t)128 * 1024];
__device__ __attribute__((aligned(256))) __bf16 g_embs[64 * 256];
__device__ __attribute__((aligned(256))) __bf16 g_embt[96 * 256];   // 70 used; pad for staging
__device__ __attribute__((aligned(256))) float  g_tblS[64 * 3072];
__device__ __attribute__((aligned(256))) float  g_tblT[70 * 3072];
__device__ __attribute__((aligned(256))) int    g_xsel[512];

__device__ __forceinline__ float fast_tanh(float x) {
    float cx = fminf(fmaxf(x, -15.f), 15.f);
    float e = __expf(-2.f * cx);
    return (1.f - e) / (1.f + e);
}

// async 16B global->LDS; LDS base must be wave-uniform (HW adds lane*16).
__device__ __forceinline__ void gload_lds16(const void* g, void* l)
{
    __builtin_amdgcn_global_load_lds(
        (const __attribute__((address_space(1))) void*)g,
        (__attribute__((address_space(3))) void*)l, 16, 0, 0);
}

// ---------------------------------------------------------------------------
__global__ void k_cvt(const float* __restrict__ src, __bf16* __restrict__ dst,
                      int n4)
{
    int i = blockIdx.x * 256 + threadIdx.x;
    if (i >= n4) return;
    float4 v = ((const float4*)src)[i];
    __bf16 o[4] = {(__bf16)v.x, (__bf16)v.y, (__bf16)v.z, (__bf16)v.w};
    *(ushort2*)(dst + 4 * i) = *(ushort2*)o;
    *(ushort2*)(dst + 4 * i + 2) = *(ushort2*)(o + 2);
}

// Row-major f32 W[R][K] -> fragment-major bf16.
__global__ void swz_rm(const float* __restrict__ W, __bf16* __restrict__ out,
                       int nK, int total)
{
    int gid = blockIdx.x * 256 + threadIdx.x;
    if (gid >= total) return;
    int F = gid >> 6, L = gid & 63;
    int t = F / nK, c = F - t * nK;
    int K = nK * 32;
    const float* s = W + (size_t)(t * 16 + (L & 15)) * K + c * 32 + (L >> 4) * 8;
    __bf16 o[8];
#pragma unroll
    for (int u = 0; u < 8; u++) o[u] = (__bf16)s[u];
    *(uint4*)(out + (size_t)gid * 8) = *(uint4*)o;
}

// Column-gather: logical W'[n][k] = W[k*ldsrc + n]; n>=nguard -> 0.
__global__ void swz_cm(const float* __restrict__ W, __bf16* __restrict__ out,
                       int nK, int ldsrc, int nguard, int total)
{
    int gid = blockIdx.x * 256 + threadIdx.x;
    if (gid >= total) return;
    int F = gid >> 6, L = gid & 63;
    int t = F / nK, c = F - t * nK;
    int n = t * 16 + (L & 15);
    int k = c * 32 + (L >> 4) * 8;
    __bf16 o[8];
#pragma unroll
    for (int u = 0; u < 8; u++)
        o[u] = (n < nguard) ? (__bf16)W[(size_t)(k + u) * ldsrc + n] : (__bf16)0.f;
    *(uint4*)(out + (size_t)gid * 8) = *(uint4*)o;
}

__global__ void k_init(float* __restrict__ out)
{
    int idx = blockIdx.x * 256 + threadIdx.x;
    if (idx < 512 * 1024) { g_h[idx] = 0.f; g_hb[0][idx] = (__bf16)0.f; }
    if (idx < 512 * 70) out[idx] = (idx % 70 == 1) ? 1.f : 0.f;
}

// ---------------------------------------------------------------------------
// k_tbl: tbl[v][n] = emb[v][:] . W[n][cOff*32 : cOff*32+256]  (K=256, 8 frags)
// ---------------------------------------------------------------------------
__global__ __launch_bounds__(256) void k_tbl(
    const __bf16* __restrict__ emb, const __bf16* __restrict__ sW,
    int nKtot, int cOff, int vguard, float* __restrict__ tbl)
{
    __shared__ __bf16 sA[32 * 256];
    const int tid = threadIdx.x;
    const int w = tid >> 6, lane = tid & 63;
    const int r15 = lane & 15, q = lane >> 4;
    const int bx = blockIdx.x, m0 = blockIdx.y * 32;

#pragma unroll
    for (int i = 0; i < 4; i++) {
        int lin = tid + i * 256;
        int r = lin >> 5, U = lin & 31;
        uint4 v = *(const uint4*)(emb + (size_t)(m0 + r) * 256 + U * 8);
        *(uint4*)(sA + (r * 32 + (U ^ (r & 7))) * 8) = v;
    }
    __syncthreads();

    const size_t tb = (size_t)(bx * 4 + w);
    const __bf16* wp = sW + (tb * nKtot + cOff) * 512 + lane * 8;
    const int xk = r15 & 7;
    const int ar0 = r15 * 256, ar1 = (16 + r15) * 256;

    f32x4 acc[2];
    acc[0] = (f32x4){0.f, 0.f, 0.f, 0.f};
    acc[1] = (f32x4){0.f, 0.f, 0.f, 0.f};
#pragma unroll
    for (int c = 0; c < 8; c++) {
        int us = ((c * 4 + q) ^ xk) * 8;
        bfx8 a0 = *(const bfx8*)(sA + ar0 + us);
        bfx8 a1 = *(const bfx8*)(sA + ar1 + us);
        bfx8 wv = *(const bfx8*)(wp + c * 512);
        acc[0] = MFMA(a0, wv, acc[0], 0, 0, 0);
        acc[1] = MFMA(a1, wv, acc[1], 0, 0, 0);
    }
    const int n = bx * 64 + w * 16 + r15;
#pragma unroll
    for (int ms = 0; ms < 2; ms++)
#pragma unroll
        for (int reg = 0; reg < 4; reg++) {
            int row = m0 + ms * 16 + q * 4 + reg;
            if (row < vguard)
                tbl[(size_t)row * 3072 + n] = acc[ms][reg];
        }
}

// ---------------------------------------------------------------------------
// k_encpart (frozen R6): XCD-swizzled, A dbuf 32KB K-chunks, LDS C-stage.
// ---------------------------------------------------------------------------
__global__ __launch_bounds__(512, 4) void k_encpart(
    const __bf16* __restrict__ Amat, const __bf16* __restrict__ sW,
    __bf16* __restrict__ Cout)
{
    __shared__ __bf16 sA[2][64 * 256];   // 2 x 32 KB
    const int tid = threadIdx.x;
    const int w = tid >> 6, lane = tid & 63;
    const int r15 = lane & 15, q = lane >> 4;
    const int sw = (blockIdx.x & 7) * 128 + (blockIdx.x >> 3);
    const int nx = sw & 3;
    const int n0 = nx * 256, m0 = (sw >> 2) * 64;

    int sr[4], sv[4], so[4];
#pragma unroll
    for (int i = 0; i < 4; i++) {
        int lin = tid + i * 512;
        sr[i] = lin >> 5;
        sv[i] = lin & 31;
        so[i] = (sr[i] * 32 + (sv[i] ^ (sr[i] & 7))) * 8;
    }

    uint4 regs[4];
#pragma unroll
    for (int i = 0; i < 4; i++)
        regs[i] = *(const uint4*)(Amat + (size_t)(m0 + sr[i]) * 1024 + sv[i] * 8);
#pragma unroll
    for (int i = 0; i < 4; i++)
        *(uint4*)(&sA[0][so[i]]) = regs[i];
    __syncthreads();

    const int xk = r15 & 7;
    f32x4 acc[2][4];
#pragma unroll
    for (int nn = 0; nn < 2; nn++)
#pragma unroll
        for (int mf = 0; mf < 4; mf++) acc[nn][mf] = (f32x4){0.f, 0.f, 0.f, 0.f};

    const __bf16* wp0 = sW + ((size_t)(nx * 16 + w * 2) * 32) * 512 + lane * 8;
    const __bf16* wp1 = wp0 + 32 * 512;
    const int ar0 = r15 * 256;
    const int ar1 = (16 + r15) * 256;
    const int ar2 = (32 + r15) * 256;
    const int ar3 = (48 + r15) * 256;

    for (int kc = 0; kc < 4; kc++) {
        if (kc < 3) {
#pragma unroll
            for (int i = 0; i < 4; i++)
                regs[i] = *(const uint4*)(Amat + (size_t)(m0 + sr[i]) * 1024 +
                                          (kc + 1) * 256 + sv[i] * 8);
        }
        const __bf16* sAb = sA[kc & 1];
        const __bf16* wq0 = wp0 + kc * 8 * 512;
        const __bf16* wq1 = wp1 + kc * 8 * 512;
#pragma unroll
        for (int c = 0; c < 8; c++) {
            int us = ((c * 4 + q) ^ xk) * 8;
            bfx8 a0 = *(const bfx8*)(sAb + ar0 + us);
            bfx8 a1 = *(const bfx8*)(sAb + ar1 + us);
            bfx8 a2 = *(const bfx8*)(sAb + ar2 + us);
            bfx8 a3 = *(const bfx8*)(sAb + ar3 + us);
            bfx8 w0 = *(const bfx8*)(wq0 + c * 512);
            bfx8 w1 = *(const bfx8*)(wq1 + c * 512);
            acc[0][0] = MFMA(a0, w0, acc[0][0], 0, 0, 0);
            acc[0][1] = MFMA(a1, w0, acc[0][1], 0, 0, 0);
            acc[0][2] = MFMA(a2, w0, acc[0][2], 0, 0, 0);
            acc[0][3] = MFMA(a3, w0, acc[0][3], 0, 0, 0);
            acc[1][0] = MFMA(a0, w1, acc[1][0], 0, 0, 0);
            acc[1][1] = MFMA(a1, w1, acc[1][1], 0, 0, 0);
            acc[1][2] = MFMA(a2, w1, acc[1][2], 0, 0, 0);
            acc[1][3] = MFMA(a3, w1, acc[1][3], 0, 0, 0);
        }
        if (kc < 3) {
#pragma unroll
            for (int i = 0; i < 4; i++)
                *(uint4*)(&sA[(kc + 1) & 1][so[i]]) = regs[i];
            __syncthreads();
        }
    }

    __bf16* sC = sA[0];
#pragma unroll
    for (int nn = 0; nn < 2; nn++) {
        const int cl = (w * 2 + nn) * 16 + r15;
#pragma unroll
        for (int mf = 0; mf < 4; mf++) {
#pragma unroll
            for (int reg = 0; reg < 4; reg++) {
                int row = mf * 16 + q * 4 + reg;
                sC[row * 256 + cl] = (__bf16)acc[nn][mf][reg];
            }
        }
    }
    __syncthreads();
#pragma unroll
    for (int i = 0; i < 4; i++) {
        int lin = tid + i * 512;
        int row = lin >> 5, unit = lin & 31;
        *(uint4*)(Cout + (size_t)(m0 + row) * 1024 + n0 + unit * 8) =
            *(const uint4*)(sC + row * 256 + unit * 8);
    }
}

// ---------------------------------------------------------------------------
#define GH_BODY(ACC)                                              \
    {                                                             \
        int us = ((c * 4 + q) ^ xk) * 8;                          \
        bfx8 a0 = *(const bfx8*)(sA1 + br0 + us);                 \
        bfx8 a1 = *(const bfx8*)(sA1 + br1 + us);                 \
        bfx8 w0 = *(const bfx8*)(xp0 + c * 512);                  \
        bfx8 w1 = *(const bfx8*)(xp1 + c * 512);                  \
        bfx8 w2 = *(const bfx8*)(xp2 + c * 512);                  \
        ACC[0][0] = MFMA(a0, w0, ACC[0][0], 0, 0, 0);             \
        ACC[0][1] = MFMA(a1, w0, ACC[0][1], 0, 0, 0);             \
        ACC[1][0] = MFMA(a0, w1, ACC[1][0], 0, 0, 0);             \
        ACC[1][1] = MFMA(a1, w1, ACC[1][1], 0, 0, 0);             \
        ACC[2][0] = MFMA(a0, w2, ACC[2][0], 0, 0, 0);             \
        ACC[2][1] = MFMA(a1, w2, ACC[2][1], 0, 0, 0);             \
    }

#define GI_BODY(ACC)                                              \
    {                                                             \
        bfx8 a0 = *(const bfx8*)(A0 + c * 32);                    \
        bfx8 a1 = *(const bfx8*)(A1 + c * 32);                    \
        bfx8 w0 = *(const bfx8*)(wp0 + c * 512);                  \
        bfx8 w1 = *(const bfx8*)(wp1 + c * 512);                  \
        bfx8 w2 = *(const bfx8*)(wp2 + c * 512);                  \
        ACC[0][0] = MFMA(a0, w0, ACC[0][0], 0, 0, 0);             \
        ACC[0][1] = MFMA(a1, w0, ACC[0][1], 0, 0, 0);             \
        ACC[1][0] = MFMA(a0, w1, ACC[1][0], 0, 0, 0);             \
        ACC[1][1] = MFMA(a1, w1, ACC[1][1], 0, 0, 0);             \
        ACC[2][0] = MFMA(a0, w2, ACC[2][0], 0, 0, 0);             \
        ACC[2][1] = MFMA(a1, w2, ACC[2][1], 0, 0, 0);             \
    }

// Stage a 32-row x 1024-col bf16 tile (64KB) into swizzled LDS via
// global_load_lds: linear LDS dest (wave-uniform base), XOR-swizzle applied
// to the per-lane global source (involution -> same final LDS image as R7).
// Wave w, iter i covers row r = 2i + (w>>1), units Ub..Ub+63 (Ub=64*(w&1)).
#define STAGE_A1(SRCP, DSTP)                                               \
    {                                                                      \
        const int Ub = (w & 1) * 64;                                       \
        const int rb = w >> 1;                                             \
        _Pragma("unroll")                                                  \
        for (int i = 0; i < 16; i++) {                                     \
            int r = 2 * i + rb;                                            \
            gload_lds16(SRCP + (size_t)(m0 + r) * 1024 +                   \
                            (((Ub + lane) ^ (r & 7)) << 3),                \
                        DSTP + (r * 128 + Ub) * 8);                        \
        }                                                                  \
    }

// ---------------------------------------------------------------------------
// gru_enc: grid (32 j, 16 m) x 256 thr, LDS 76KB. gi from g_tblS (epilogue
// gather). All 4 waves gh from LDS-staged A1: w<2 c[0,16), w>=2 c[16,32)
// -> sGh handoff.
// ---------------------------------------------------------------------------
__global__ __launch_bounds__(256, 2) void gru_enc(
    const __bf16* __restrict__ hb_in, __bf16* __restrict__ hb_out,
    const float* __restrict__ b1, const float* __restrict__ b2,
    const int* __restrict__ src_t, int enc_t)
{
    __shared__ __align__(16) unsigned char smem[77824];
    __bf16* sA1 = (__bf16*)smem;            // 64 KB
    float*  sGh = (float*)(smem + 65536);   // 12 KB
    const int tid = threadIdx.x;
    const int w = tid >> 6, lane = tid & 63;
    const int r15 = lane & 15, q = lane >> 4;
    const int j0 = blockIdx.x * 32, m0 = blockIdx.y * 32;
    const int jsub = w & 1;

    STAGE_A1(hb_in, sA1)
    __syncthreads();

    const size_t tb = (size_t)(blockIdx.x * 2 + jsub);
    const int xk = r15 & 7;
    f32x4 acc[3][2];
#pragma unroll
    for (int s = 0; s < 3; s++)
#pragma unroll
        for (int ms = 0; ms < 2; ms++) acc[s][ms] = (f32x4){0.f, 0.f, 0.f, 0.f};

    const __bf16* xp0 = g_sWhhe + (tb * 32) * 512 + lane * 8;
    const __bf16* xp1 = g_sWhhe + ((tb + 64) * 32) * 512 + lane * 8;
    const __bf16* xp2 = g_sWhhe + ((tb + 128) * 32) * 512 + lane * 8;
    const int br0 = r15 * 1024, br1 = (16 + r15) * 1024;
    const int cbeg = (w < 2) ? 0 : 16;
#pragma unroll 8
    for (int c = cbeg; c < cbeg + 16; c++) GH_BODY(acc)

    if (w >= 2) {
#pragma unroll
        for (int s = 0; s < 3; s++)
#pragma unroll
            for (int ms = 0; ms < 2; ms++)
#pragma unroll
                for (int reg = 0; reg < 4; reg++)
                    sGh[((s * 2 + jsub) * 32 + ms * 16 + q * 4 + reg) * 16 + r15] =
                        acc[s][ms][reg];
    }
    __syncthreads();
    if (w < 2) {
        const int jj = j0 + jsub * 16 + r15;
        const float bb1[3] = {b1[jj], b1[1024 + jj], b1[2048 + jj]};
        const float bb2[3] = {b2[jj], b2[1024 + jj], b2[2048 + jj]};
#pragma unroll
        for (int ms = 0; ms < 2; ms++) {
#pragma unroll
            for (int reg = 0; reg < 4; reg++) {
                int bl = ms * 16 + q * 4 + reg;
                int b_ = m0 + bl;
                int xv = src_t[b_];
                xv = (xv < 0) ? 0 : (xv > 63 ? 63 : xv);
                const float* tv = g_tblS + (size_t)xv * 3072 + jj;
                float gh0 = acc[0][ms][reg] + bb1[0] +
                            sGh[((0 * 2 + jsub) * 32 + bl) * 16 + r15];
                float gh1 = acc[1][ms][reg] + bb1[1] +
                            sGh[((1 * 2 + jsub) * 32 + bl) * 16 + r15];
                float gh2 = acc[2][ms][reg] + bb1[2] +
                            sGh[((2 * 2 + jsub) * 32 + bl) * 16 + r15];
                float gi0 = tv[0]    + bb2[0];
                float gi1 = tv[1024] + bb2[1];
                float gi2 = tv[2048] + bb2[2];
                float r = 1.f / (1.f + __expf(-(gi0 + gh0)));
                float z = 1.f / (1.f + __expf(-(gi1 + gh1)));
                float n = fast_tanh(gi2 + r * gh2);
                size_t off = (size_t)b_ * 1024 + jj;
                float hv = (1.f - z) * n + z * g_h[off];
                g_h[off] = hv;
                hb_out[off] = (__bf16)hv;
                g_enc_ops[(size_t)enc_t * 524288 + off] = (__bf16)hv;
            }
        }
    }
}

// ---------------------------------------------------------------------------
// gru_dec: waves 0-1 gh (32 frags, LDS-staged h), waves 2-3 gi ctx-part
// (32 frags, Adec direct) -> sGi handoff. Emb gi from g_tblT[g_xsel[b]].
// ---------------------------------------------------------------------------
__global__ __launch_bounds__(256, 2) void gru_dec(
    const __bf16* __restrict__ hb_in, __bf16* __restrict__ hb_out,
    const float* __restrict__ b1, const float* __restrict__ b2)
{
    __shared__ __align__(16) unsigned char smem[77824];
    __bf16* sA1 = (__bf16*)smem;            // 64 KB
    float*  sGi = (float*)(smem + 65536);   // 12 KB
    const int tid = threadIdx.x;
    const int w = tid >> 6, lane = tid & 63;
    const int r15 = lane & 15, q = lane >> 4;
    const int j0 = blockIdx.x * 32, m0 = blockIdx.y * 32;
    const int jsub = w & 1;

    STAGE_A1(hb_in, sA1)
    __syncthreads();

    const size_t tb = (size_t)(blockIdx.x * 2 + jsub);
    const int xk = r15 & 7;
    f32x4 acc[3][2];
#pragma unroll
    for (int s = 0; s < 3; s++)
#pragma unroll
        for (int ms = 0; ms < 2; ms++) acc[s][ms] = (f32x4){0.f, 0.f, 0.f, 0.f};

    if (w < 2) {
        const __bf16* xp0 = g_sWhhd + (tb * 32) * 512 + lane * 8;
        const __bf16* xp1 = g_sWhhd + ((tb + 64) * 32) * 512 + lane * 8;
        const __bf16* xp2 = g_sWhhd + ((tb + 128) * 32) * 512 + lane * 8;
        const int br0 = r15 * 1024, br1 = (16 + r15) * 1024;
#pragma unroll 8
        for (int c = 0; c < 32; c++) GH_BODY(acc)
    } else {
        const __bf16* A0 = g_Adec + (size_t)(m0 + r15) * 1024 + q * 8;
        const __bf16* A1 = A0 + 16 * 1024;
        const __bf16* wp0 = g_sWihd + (tb * 40) * 512 + lane * 8;
        const __bf16* wp1 = g_sWihd + ((tb + 64) * 40) * 512 + lane * 8;
        const __bf16* wp2 = g_sWihd + ((tb + 128) * 40) * 512 + lane * 8;
#pragma unroll 8
        for (int c = 0; c < 32; c++) GI_BODY(acc)
#pragma unroll
        for (int s = 0; s < 3; s++)
#pragma unroll
            for (int ms = 0; ms < 2; ms++)
#pragma unroll
                for (int reg = 0; reg < 4; reg++)
                    sGi[((s * 2 + jsub) * 32 + ms * 16 + q * 4 + reg) * 16 + r15] =
                        acc[s][ms][reg];
    }
    __syncthreads();
    if (w < 2) {
        const int jj = j0 + jsub * 16 + r15;
        const float bb1[3] = {b1[jj], b1[1024 + jj], b1[2048 + jj]};
        const float bb2[3] = {b2[jj], b2[1024 + jj], b2[2048 + jj]};
#pragma unroll
        for (int ms = 0; ms < 2; ms++) {
#pragma unroll
            for (int reg = 0; reg < 4; reg++) {
                int bl = ms * 16 + q * 4 + reg;
                int b_ = m0 + bl;
                const float* tv = g_tblT + (size_t)g_xsel[b_] * 3072 + jj;
                float gh0 = acc[0][ms][reg] + bb1[0];
                float gh1 = acc[1][ms][reg] + bb1[1];
                float gh2 = acc[2][ms][reg] + bb1[2];
                float gi0 = sGi[((0 * 2 + jsub) * 32 + bl) * 16 + r15] +
                            tv[0]    + bb2[0];
                float gi1 = sGi[((1 * 2 + jsub) * 32 + bl) * 16 + r15] +
                            tv[1024] + bb2[1];
                float gi2 = sGi[((2 * 2 + jsub) * 32 + bl) * 16 + r15] +
                            tv[2048] + bb2[2];
                float r = 1.f / (1.f + __expf(-(gi0 + gh0)));
                float z = 1.f / (1.f + __expf(-(gi1 + gh1)));
                float n = fast_tanh(gi2 + r * gh2);
                size_t off = (size_t)b_ * 1024 + jj;
                float hv = (1.f - z) * n + z * g_h[off];
                g_h[off] = hv;
                hb_out[off] = (__bf16)hv;
            }
        }
    }
}

// ---------------------------------------------------------------------------
// Fused [hpart | logits] from h (bf16). grid (18, 16). bx<16: hpart col-tile;
// bx 16..17: logits (guard 70) -> out row lrow (skipped if lrow<0).
// ---------------------------------------------------------------------------
__global__ __launch_bounds__(256) void k_hl(
    const __bf16* __restrict__ src, const float* __restrict__ battn,
    const float* __restrict__ bout, int lrow, float* __restrict__ outp)
{
    __shared__ __bf16 sA1[32 * 1024];
    const int tid = threadIdx.x;
    const int w = tid >> 6, lane = tid & 63;
    const int r15 = lane & 15, q = lane >> 4;
    const int bx = blockIdx.x, m0 = blockIdx.y * 32;

    STAGE_A1(src, sA1)
    __syncthreads();

    const __bf16* sW;
    int n;
    if (bx < 16) {
        sW = g_sWattnA;
        n = bx * 64 + w * 16 + r15;
    } else {
        if (lrow < 0) return;
        sW = g_sWout;
        n = (bx - 16) * 64 + w * 16 + r15;
    }
    const size_t tb = (size_t)((bx < 16 ? bx : bx - 16) * 4 + w);
    const __bf16* wp = sW + (tb * 32) * 512 + lane * 8;
    const int xk = r15 & 7;
    const int ar0 = r15 * 1024, ar1 = (16 + r15) * 1024;

    f32x4 acc[2];
    acc[0] = (f32x4){0.f, 0.f, 0.f, 0.f};
    acc[1] = (f32x4){0.f, 0.f, 0.f, 0.f};
#pragma unroll 8
    for (int c = 0; c < 32; c++) {
        int us = ((c * 4 + q) ^ xk) * 8;
        bfx8 a0 = *(const bfx8*)(sA1 + ar0 + us);
        bfx8 a1 = *(const bfx8*)(sA1 + ar1 + us);
        bfx8 wv = *(const bfx8*)(wp + c * 512);
        acc[0] = MFMA(a0, wv, acc[0], 0, 0, 0);
        acc[1] = MFMA(a1, wv, acc[1], 0, 0, 0);
    }

    if (bx < 16) {
        float bv = battn[n];
#pragma unroll
        for (int ms = 0; ms < 2; ms++)
#pragma unroll
            for (int reg = 0; reg < 4; reg++)
                g_hpart[(size_t)(m0 + ms * 16 + q * 4 + reg) * 1024 + n] =
                    acc[ms][reg] + bv;
    } else if (n < 70) {
        float bv = bout[n];
#pragma unroll
        for (int ms = 0; ms < 2; ms++)
#pragma unroll
            for (int reg = 0; reg < 4; reg++)
                outp[(size_t)lrow * 35840 +
                     (size_t)(m0 + ms * 16 + q * 4 + reg) * 70 + n] =
                    acc[ms][reg] + bv;
    }
}

// ---------------------------------------------------------------------------
// Attention step: x-select (-> g_xsel) + scores + softmax + alpha out + ctx.
// One block per batch b.
// ---------------------------------------------------------------------------
__global__ __launch_bounds__(256) void k_attn(
    int j, const int* __restrict__ target, const int* __restrict__ tf,
    const float* __restrict__ v_attn, float* __restrict__ out)
{
    const int b = blockIdx.x, tid = threadIdx.x;
    const int lane = tid & 63, wave = tid >> 6;
    __shared__ float sc[32], sal[32];
    __shared__ int sx;
    if (wave == 0) {
        int xv;
        if (j == 0) xv = target[b];
        else if (*tf) xv = target[j * 512 + b];
        else {
            const float* row = out + (size_t)j * 35840 + b * 70;
            float bv = row[lane]; int bi = lane;
            if (lane < 6) {
                float v2 = row[lane + 64];
                if (v2 > bv) { bv = v2; bi = lane + 64; }
            }
#pragma unroll
            for (int off = 32; off; off >>= 1) {
                float ov = __shfl_down(bv, off);
                int   oi = __shfl_down(bi, off);
                if (ov > bv || (ov == bv && oi < bi)) { bv = ov; bi = oi; }
            }
            xv = bi;
        }
        if (lane == 0) sx = (xv < 0) ? 0 : (xv > 69 ? 69 : xv);
    }
    float hpv[16], vsv[16];
    {
        const float* hp = g_hpart + (size_t)b * 1024;
#pragma unroll
        for (int u = 0; u < 8; u++) {
            hpv[u]     = hp[lane * 8 + u];
            hpv[8 + u] = hp[512 + lane * 8 + u];
            vsv[u]     = v_attn[lane * 8 + u];
            vsv[8 + u] = v_attn[512 + lane * 8 + u];
        }
    }
    __syncthreads();
    if (tid == 0) g_xsel[b] = sx;
    for (int s = wave * 8; s < wave * 8 + 8; s++) {
        const __bf16* ep = g_enc_part + ((size_t)s * 512 + b) * 1024;
        bfx8 e0 = *(const bfx8*)(ep + lane * 8);
        bfx8 e1 = *(const bfx8*)(ep + 512 + lane * 8);
        float part = 0.f;
#pragma unroll
        for (int u = 0; u < 8; u++) {
            part += vsv[u]     * fast_tanh((float)e0[u] + hpv[u]);
            part += vsv[8 + u] * fast_tanh((float)e1[u] + hpv[8 + u]);
        }
#pragma unroll
        for (int off = 32; off; off >>= 1) part += __shfl_down(part, off);
        if (lane == 0) sc[s] = part;
    }
    __syncthreads();
    float mx = sc[0];
#pragma unroll
    for (int s = 1; s < 32; s++) mx = fmaxf(mx, sc[s]);
    float den = 0.f;
#pragma unroll
    for (int s = 0; s < 32; s++) den += __expf(sc[s] - mx);
    float rden = 1.f / den;
    if (tid < 32) {
        float al = __expf(sc[tid] - mx) * rden;
        sal[tid] = al;
        out[1146880 + (size_t)j * 16384 + b * 32 + tid] = al;
    }
    __syncthreads();
    float c0 = 0, c1 = 0, c2 = 0, c3 = 0;
    const __bf16* eo = g_enc_ops + (size_t)b * 1024 + tid * 4;
#pragma unroll 4
    for (int s = 0; s < 32; s++) {
        bfx4 e = *(const bfx4*)(eo + (size_t)s * 524288);
        float al = sal[s];
        c0 += al * (float)e[0]; c1 += al * (float)e[1];
        c2 += al * (float)e[2]; c3 += al * (float)e[3];
    }
    bfx4 o = {(__bf16)c0, (__bf16)c1, (__bf16)c2, (__bf16)c3};
    *(bfx4*)(&g_Adec[(size_t)b * 1024 + tid * 4]) = o;
}

// ---------------------------------------------------------------------------
extern "C" void kernel_launch(void* const* d_in, const int* in_sizes, int n_in,
                              void* d_out, int out_size, void* d_ws, size_t ws_size,
                              hipStream_t stream)
{
    const int*   source   = (const int*)d_in[0];
    const int*   target   = (const int*)d_in[1];
    const int*   tf       = (const int*)d_in[2];
    const float* emb_src  = (const float*)d_in[3];
    const float* W_ih_enc = (const float*)d_in[4];
    const float* W_hh_enc = (const float*)d_in[5];
    const float* b_ih_enc = (const float*)d_in[6];
    const float* b_hh_enc = (const float*)d_in[7];
    const float* emb_tgt  = (const float*)d_in[8];
    const float* W_attn   = (const float*)d_in[9];
    const float* b_attn   = (const float*)d_in[10];
    const float* v_attn   = (const float*)d_in[11];
    const float* W_ih_dec = (const float*)d_in[12];
    const float* W_hh_dec = (const float*)d_in[13];
    const float* b_ih_dec = (const float*)d_in[14];
    const float* b_hh_dec = (const float*)d_in[15];
    const float* W_out    = (const float*)d_in[16];
    const float* b_out    = (const float*)d_in[17];
    float* out = (float*)d_out;

    void *p_hb, *p_sWhhe, *p_sWihe, *p_sWhhd, *p_sWihd, *p_sWattnA, *p_sWattnB,
         *p_sWout, *p_embs, *p_embt, *p_enc_ops, *p_enc_part, *p_tblS, *p_tblT;
    hipGetSymbolAddress(&p_hb,       HIP_SYMBOL(g_hb));
    hipGetSymbolAddress(&p_sWhhe,    HIP_SYMBOL(g_sWhhe));
    hipGetSymbolAddress(&p_sWihe,    HIP_SYMBOL(g_sWihe));
    hipGetSymbolAddress(&p_sWhhd,    HIP_SYMBOL(g_sWhhd));
    hipGetSymbolAddress(&p_sWihd,    HIP_SYMBOL(g_sWihd));
    hipGetSymbolAddress(&p_sWattnA,  HIP_SYMBOL(g_sWattnA));
    hipGetSymbolAddress(&p_sWattnB,  HIP_SYMBOL(g_sWattnB));
    hipGetSymbolAddress(&p_sWout,    HIP_SYMBOL(g_sWout));
    hipGetSymbolAddress(&p_embs,     HIP_SYMBOL(g_embs));
    hipGetSymbolAddress(&p_embt,     HIP_SYMBOL(g_embt));
    hipGetSymbolAddress(&p_enc_ops,  HIP_SYMBOL(g_enc_ops));
    hipGetSymbolAddress(&p_enc_part, HIP_SYMBOL(g_enc_part));
    hipGetSymbolAddress(&p_tblS,     HIP_SYMBOL(g_tblS));
    hipGetSymbolAddress(&p_tblT,     HIP_SYMBOL(g_tblT));
    __bf16* hb0 = (__bf16*)p_hb;
    __bf16* hb1 = hb0 + 512 * 1024;

    // ---- one-time setup ----
    k_cvt<<<16, 256, 0, stream>>>(emb_src, (__bf16*)p_embs, 64 * 256 / 4);
    k_cvt<<<18, 256, 0, stream>>>(emb_tgt, (__bf16*)p_embt, 70 * 256 / 4);
    swz_rm<<<1536, 256, 0, stream>>>(W_hh_enc, (__bf16*)p_sWhhe, 32, 393216);
    swz_rm<<<384,  256, 0, stream>>>(W_ih_enc, (__bf16*)p_sWihe, 8,  98304);
    swz_rm<<<1536, 256, 0, stream>>>(W_hh_dec, (__bf16*)p_sWhhd, 32, 393216);
    swz_rm<<<1920, 256, 0, stream>>>(W_ih_dec, (__bf16*)p_sWihd, 40, 491520);
    swz_cm<<<512,  256, 0, stream>>>(W_attn, (__bf16*)p_sWattnA, 32, 1024, 1024, 131072);
    swz_cm<<<512,  256, 0, stream>>>(W_attn + (size_t)1024 * 1024,
                                     (__bf16*)p_sWattnB, 32, 1024, 1024, 131072);
    swz_cm<<<64,   256, 0, stream>>>(W_out,  (__bf16*)p_sWout,   32, 70,   70,   16384);
    // gi tables: tblS = emb_src @ W_ih_enc^T ; tblT = emb_tgt @ W_ih_dec[:,H:]^T
    k_tbl<<<dim3(48, 2), 256, 0, stream>>>(
        (__bf16*)p_embs, (__bf16*)p_sWihe, 8,  0,  64, (float*)p_tblS);
    k_tbl<<<dim3(48, 3), 256, 0, stream>>>(
        (__bf16*)p_embt, (__bf16*)p_sWihd, 40, 32, 70, (float*)p_tblT);
    k_init<<<2048, 256, 0, stream>>>(out);

    // -------- Encoder: 32 steps --------
    for (int t = 0; t < 32; t++) {
        __bf16* hin  = (t & 1) ? hb1 : hb0;
        __bf16* hout = (t & 1) ? hb0 : hb1;
        gru_enc<<<dim3(32, 16), 256, 0, stream>>>(
            hin, hout, b_hh_enc, b_ih_enc, source + t * 512, t);
    }
    // h_enc lands in hb0

    // enc_part = enc_ops @ W_attn[H:2H]^T  (frag-major weights, no bias)
    k_encpart<<<dim3(1024), 512, 0, stream>>>(
        (__bf16*)p_enc_ops, (__bf16*)p_sWattnB, (__bf16*)p_enc_part);

    // hpart for step 0
    k_hl<<<dim3(18, 16), 256, 0, stream>>>(hb0, b_attn, b_out, -1, out);

    // -------- Decoder: 31 steps --------
    for (int j = 0; j < 31; j++) {
        __bf16* hin  = (j & 1) ? hb1 : hb0;
        __bf16* hout = (j & 1) ? hb0 : hb1;
        k_attn<<<512, 256, 0, stream>>>(j, target, tf, v_attn, out);
        gru_dec<<<dim3(32, 16), 256, 0, stream>>>(hin, hout, b_hh_dec, b_ih_dec);
        k_hl<<<dim3(18, 16), 256, 0, stream>>>(hout, b_attn, b_out, j + 1, out);
    }
}